// Round 6
// baseline (274.662 us; speedup 1.0000x reference)
//
#include <hip/hip_runtime.h>
#include <stdint.h>

// out[b, seg, np, chunk, p, 4, 4] = mean over chunk frames of [x;1][x;1]^T
// (cov + mu muT == E[y yT]).  stypes 0/1/2: chunk len 136/68/45, out segs
// {0},{1,2},{3,4,5}.  Tail chunks run to T=2048 (144/1096/1418 frames).
//
// One block per b (256 x 1024 = 1 block/CU):
//  - pieces = raw union of all chunk boundaries (36 segments, <=144 frames)
//  - lead-1 double-buffered global_load_lds staging (43 KB/buffer); the
//    piece-top __syncthreads drains exactly the one needed DMA
//  - threads 0..199 = (j<25, ph<8): 9 prefix sums in regs over frames
//    g % 8 == ph; per-stype 9 "mark" regs; chunk sum = run - mark (VALU)
//  - cross-phase reduce = 3x shfl_xor inside the 8-lane j-group
//  - wave 15 reads the 225-float red row, emits coalesced float4 stores
//  - chunk-end barriers are raw lgkmcnt-only (never drain the prefetch)

#define NSEG_MAX 40
#define IDXPK 0x9210287517640543ull   // 4x4 row r -> moment idx nibbles (9=dummy)

struct Tab {
    int n;                        // 36
    uint32_t p[NSEG_MAX];         // f0 | (len<<16)
    uint32_t meta[NSEG_MAX];      // c0 | c1<<4 | c2<<8 | endmask<<12
};

__device__ __forceinline__ void ebar() {   // LDS-only barrier: no vmcnt drain
    asm volatile("s_waitcnt lgkmcnt(0)\n\ts_barrier" ::: "memory");
}

__global__ __launch_bounds__(1024) void fused2(const float* __restrict__ x,
                                               float* __restrict__ out, Tab tab) {
    __shared__ float sx[2][10816];   // 2 x 43.3 KB staging (max piece 144 fr)
    __shared__ float red[240];       // 225 chunk sums (+pad for dummy idx 9)
    int tid = threadIdx.x;
    int b = blockIdx.x;
    const float* xb = x + (size_t)b * 153600;
    int wv = tid >> 6;

    float run[9], mark0[9], mark1[9], mark2[9];
    #pragma unroll
    for (int i = 0; i < 9; ++i) { run[i]=0.f; mark0[i]=0.f; mark1[i]=0.f; mark2[i]=0.f; }

    int j = tid >> 3, ph = tid & 7;   // compute threads: tid < 200

    // issue piece 0 into sx[0]
    {
        uint32_t pk = tab.p[0];
        int f0 = pk & 0xffff, L = (int)(pk >> 16);
        int w0 = f0 * 75, bf = w0 & ~3;
        int nv4 = (w0 - bf + L * 75 + 3) >> 2;
        const float4* src = (const float4*)(xb + bf);
        #pragma unroll
        for (int k = 0; k < 3; ++k) {
            int i = k * 1024 + tid;
            if (i < nv4)
                __builtin_amdgcn_global_load_lds(
                    (const __attribute__((address_space(1))) void*)(src + i),
                    (__attribute__((address_space(3))) void*)(&sx[0][(k * 1024 + wv * 64) * 4]),
                    16, 0, 0);
        }
    }

    int n = tab.n;
    for (int p = 0; p < n; ++p) {
        __syncthreads();              // drains DMA(p) (issued one piece ago)
        int buf = p & 1;
        if (p + 1 < n) {              // prefetch p+1 into the other buffer
            uint32_t pk = tab.p[p + 1];
            int f0 = pk & 0xffff, L = (int)(pk >> 16);
            int w0 = f0 * 75, bf = w0 & ~3;
            int nv4 = (w0 - bf + L * 75 + 3) >> 2;
            const float4* src = (const float4*)(xb + bf);
            #pragma unroll
            for (int k = 0; k < 3; ++k) {
                int i = k * 1024 + tid;
                if (i < nv4)
                    __builtin_amdgcn_global_load_lds(
                        (const __attribute__((address_space(1))) void*)(src + i),
                        (__attribute__((address_space(3))) void*)(&sx[buf ^ 1][(k * 1024 + wv * 64) * 4]),
                        16, 0, 0);
            }
        }

        uint32_t pk = tab.p[p];
        int f0 = pk & 0xffff, L = (int)(pk >> 16);
        if (tid < 200) {
            const float* s = &sx[buf][(f0 * 75) & 3];
            int l0 = (ph - f0) & 7;           // two's complement & == mod 8
            for (int l = l0; l < L; l += 8) {
                const float* q = s + l * 75 + j * 3;
                float a = q[0], bb = q[1], c = q[2];
                run[0] += a;      run[1] += bb;     run[2] += c;
                run[3] += a * a;  run[4] += a * bb; run[5] += a * c;
                run[6] += bb * bb; run[7] += bb * c; run[8] += c * c;
            }
        }

        // chunk ends at this piece boundary (every piece ends >=1 chunk)
        uint32_t mt = tab.meta[p];
        uint32_t em = mt >> 12;
        for (int st = 0; st < 3; ++st) {
            if (!((em >> st) & 1)) continue;       // block-uniform
            int ch = (mt >> (4 * st)) & 15;
            if (tid < 200) {
                float* mk = (st == 0) ? mark0 : (st == 1) ? mark1 : mark2;
                float d[9];
                #pragma unroll
                for (int i = 0; i < 9; ++i) { d[i] = run[i] - mk[i]; mk[i] = run[i]; }
                #pragma unroll
                for (int i = 0; i < 9; ++i) {
                    d[i] += __shfl_xor(d[i], 1);
                    d[i] += __shfl_xor(d[i], 2);
                    d[i] += __shfl_xor(d[i], 4);   // all 8 lanes hold full sum
                }
                float v = d[0];
                #pragma unroll
                for (int i = 1; i < 8; ++i) v = (ph == i) ? d[i] : v;
                red[j * 9 + ph] = v;
                if (ph == 0) red[j * 9 + 8] = d[8];
            }
            ebar();                                // red visible (lgkm only)
            if (wv == 15) {                        // dedicated storer wave
                int ns  = (st == 0) ? 136 : (st == 1) ? 68 : 45;
                int nfr = (ch == 14) ? (2048 - 14 * ns) : ns;
                float inv = 1.0f / (float)nfr;
                int so0 = (st == 0) ? 0 : (st == 1) ? 1 : 3;
                int Q = (st + 1) * 100;            // float4 count (dups incl.)
                float4* ob4 = (float4*)(out + (size_t)b * 36000);
                int lane = tid - 960;
                for (int q2 = lane; q2 < Q; q2 += 64) {
                    int dup = q2 / 100, r2 = q2 - dup * 100;
                    int jj = r2 >> 2, r = r2 & 3;
                    int np_ = jj / 5, pp = jj - np_ * 5;
                    const float* rb = &red[jj * 9];
                    uint64_t pkk = IDXPK >> (16 * r);
                    float4 v;
                    v.x = rb[(int)(pkk & 15)] * inv;
                    v.y = rb[(int)((pkk >> 4) & 15)] * inv;
                    v.z = rb[(int)((pkk >> 8) & 15)] * inv;
                    v.w = (r == 3) ? 1.0f : rb[(int)((pkk >> 12) & 15)] * inv;
                    ob4[(so0 + dup) * 1500 + np_ * 300 + ch * 20 + pp * 4 + r] = v;
                }
            }
            ebar();                                // red free for next stype
        }
    }
}

// ---------------- Host ----------------
static void build_tab(Tab& tab) {
    unsigned char isb[2049];
    for (int i = 0; i <= 2048; ++i) isb[i] = 0;
    isb[2048] = 1;
    for (int k = 1; k <= 14; ++k) { isb[45 * k] = 1; isb[68 * k] = 1; isb[136 * k] = 1; }
    const int nst[3] = {136, 68, 45};
    int n = 0, prev = 0;
    for (int f = 1; f <= 2048; ++f) {
        if (!isb[f]) continue;
        tab.p[n] = (uint32_t)(prev | ((f - prev) << 16));
        uint32_t m = 0;
        for (int st = 0; st < 3; ++st) {
            int ns = nst[st];
            int c = prev / ns; if (c > 14) c = 14;
            int bnd = (c == 14) ? 2048 : (c + 1) * ns;
            m |= (uint32_t)c << (4 * st);
            if (f == bnd) m |= 1u << (12 + st);
        }
        tab.meta[n++] = m;
        prev = f;
    }
    tab.n = n;   // 36
}

extern "C" void kernel_launch(void* const* d_in, const int* in_sizes, int n_in,
                              void* d_out, int out_size, void* d_ws, size_t ws_size,
                              hipStream_t stream) {
    const float* x = (const float*)d_in[0];
    float* out = (float*)d_out;
    Tab tab;
    build_tab(tab);
    fused2<<<256, 1024, 0, stream>>>(x, out, tab);
}

// Round 7
// 237.831 us; speedup vs baseline: 1.1549x; 1.1549x over previous
//
#include <hip/hip_runtime.h>
#include <stdint.h>

// out[b, seg, np, chunk, p, 4, 4] = mean over chunk frames of [x;1][x;1]^T
// (cov + mu muT == E[y yT]).  stypes 0/1/2: chunk len 136/68/45, out segs
// {0},{1,2},{3,4,5}.  Tail chunks run to T=2048.
//
// p1: grid (piece, b) = 36 x 256 blocks, 256 thr. pieces = raw union of all
//     chunk boundaries (36 segments, 8..144 frames, never cross any chunk
//     edge). Thread t<250 = (fslot=t/25, j=t%25) accumulates 9 moments in
//     REGISTERS straight from global: per step k the block's 250 lanes read
//     floats f0*75+3t+750k .. +749 -- perfectly contiguous, no LDS, no
//     barriers in the load path. One LDS reduction at the end -> ws.
// p2: per (b,np): gather contiguous piece-range sums per chunk
//     (host-precomputed), finalize 4x4s, coalesced float4 stores.

#define NSEG_MAX 40
#define IDXPK 0x9210287517640543ull   // 4x4 row r -> moment idx nibbles (9=dummy)

struct Tab {
    int n;                        // 36
    uint32_t p[NSEG_MAX];         // f0 | (len<<16)
    uint32_t cr[45];              // per (stype*15+chunk): pstart | (pend<<16)
};

// ---------------- Phase 1 ----------------
__global__ __launch_bounds__(256) void p1_kernel(const float* __restrict__ x,
                                                 float* __restrict__ ws, Tab tab) {
    __shared__ float lds[2250];   // [250 threads][9]
    int pc = blockIdx.x, b = blockIdx.y;
    uint32_t pk = tab.p[pc];
    int f0 = pk & 0xffff, L = (int)(pk >> 16);   // 8 <= L <= 144
    int tid = threadIdx.x;

    float s0=0.f,s1=0.f,s2=0.f,s3=0.f,s4=0.f,s5=0.f,s6=0.f,s7=0.f,s8=0.f;
    if (tid < 250) {
        int fslot = tid / 25;                    // 0..9
        const float* q = x + (size_t)b * 153600 + (size_t)f0 * 75 + tid * 3;
        int nk = (L - fslot + 9) / 10;           // frames fslot, fslot+10, ...
        #pragma unroll 3
        for (int k = 0; k < nk; ++k, q += 750) {
            float a = q[0], bb = q[1], c = q[2];
            s0 += a;      s1 += bb;     s2 += c;
            s3 += a * a;  s4 += a * bb; s5 += a * c;
            s6 += bb * bb; s7 += bb * c; s8 += c * c;
        }
        float* l = &lds[tid * 9];                // stride 9: conflict-benign
        l[0]=s0; l[1]=s1; l[2]=s2; l[3]=s3; l[4]=s4; l[5]=s5; l[6]=s6; l[7]=s7; l[8]=s8;
    }
    __syncthreads();
    if (tid < 225) {              // cell = j*9+si ; partial at lds[fs*225+cell]
        float v = 0.f;
        #pragma unroll
        for (int fs = 0; fs < 10; ++fs) v += lds[fs * 225 + tid];
        ws[((size_t)b * tab.n + pc) * 225 + tid] = v;
    }
}

// ---------------- Phase 2: per (b, np) ----------------
__global__ __launch_bounds__(256) void p2_kernel(const float* __restrict__ ws,
                                                 float* __restrict__ out, Tab tab) {
    __shared__ float sws[1620];   // [piece][j_local*9+si], 36*45
    __shared__ float red[2032];   // [stype*15+chunk][j_local*9+si] (+pad)
    __shared__ float invn[45];
    int b = blockIdx.x, np = blockIdx.y;
    int tid = threadIdx.x;
    int n = tab.n;
    int tot = n * 45;
    const float* wb = ws + (size_t)b * n * 225 + np * 45;
    for (int i = tid; i < tot; i += 256) {
        int piece = i / 45, idx = i - piece * 45;
        sws[i] = wb[(size_t)piece * 225 + idx];   // 180 B contiguous runs
    }
    if (tid < 45) {
        int st = tid / 15, ch = tid - st * 15;
        const int nst[3] = {136, 68, 45};
        int ns = nst[st];
        int nfr = (ch == 14) ? (2048 - 14 * ns) : ns;
        invn[tid] = 1.0f / (float)nfr;
    }
    __syncthreads();

    for (int i = tid; i < 2025; i += 256) {
        int sc = i / 45, idx = i - sc * 45;
        uint32_t r = tab.cr[sc];
        int p0 = (int)(r & 0xffff), p1 = (int)(r >> 16);
        float v = 0.f;
        for (int p = p0; p < p1; ++p) v += sws[p * 45 + idx];
        red[i] = v;
    }
    __syncthreads();

    // 1800 float4 stores per block: q -> (seg, chunk, p, row)
    float4* ob4 = (float4*)(out + (size_t)b * 36000 + (size_t)np * 1200);
    for (int q = tid; q < 1800; q += 256) {
        int seg = q / 300;
        int q2  = q - seg * 300;        // ch*20 + p*4 + r
        int ch  = q2 / 20;
        int rem = q2 - ch * 20;
        int p   = rem >> 2;
        int r   = rem & 3;
        int st  = (seg == 0) ? 0 : (seg < 3) ? 1 : 2;
        int sc  = st * 15 + ch;
        float inv = invn[sc];
        const float* rb = &red[sc * 45 + p * 9];
        uint64_t pkk = IDXPK >> (16 * r);
        float4 v;
        v.x = rb[(int)(pkk & 15)] * inv;
        v.y = rb[(int)((pkk >> 4) & 15)] * inv;
        v.z = rb[(int)((pkk >> 8) & 15)] * inv;
        v.w = (r == 3) ? 1.0f : rb[(int)((pkk >> 12) & 15)] * inv;
        ob4[(size_t)seg * 1500 + q2] = v;
    }
}

// ---------------- Fallback (round-1 fused, known-correct) ----------------
__global__ __launch_bounds__(256) void gauss_fallback(const float* __restrict__ x,
                                                      float* __restrict__ out) {
    __shared__ float lds[2250];
    __shared__ float red[225];
    __shared__ float outm[400];
    int bid = blockIdx.x;
    int chunk = bid % 15;
    int tmp = bid / 15;
    int stype = tmp % 3;
    int b = tmp / 3;
    const int nbs[3] = {136, 68, 45};
    int ns = nbs[stype];
    int f0 = chunk * ns;
    int f1 = (chunk == 14) ? 2048 : (f0 + ns);
    float inv_n = 1.0f / (float)(f1 - f0);
    int tid = threadIdx.x;
    if (tid < 250) {
        int j = tid % 25, tsub = tid / 25;
        const float* base = x + (size_t)b * 153600 + j * 3;
        float s0=0.f,s1=0.f,s2=0.f,s3=0.f,s4=0.f,s5=0.f,s6=0.f,s7=0.f,s8=0.f;
        for (int t = f0 + tsub; t < f1; t += 10) {
            const float* p = base + (size_t)t * 75;
            float x0 = p[0], x1 = p[1], x2 = p[2];
            s0+=x0; s1+=x1; s2+=x2;
            s3+=x0*x0; s4+=x0*x1; s5+=x0*x2;
            s6+=x1*x1; s7+=x1*x2; s8+=x2*x2;
        }
        float* l = &lds[tid * 9];
        l[0]=s0; l[1]=s1; l[2]=s2; l[3]=s3; l[4]=s4; l[5]=s5; l[6]=s6; l[7]=s7; l[8]=s8;
    }
    __syncthreads();
    if (tid < 225) {
        float v = 0.f;
        #pragma unroll
        for (int ts = 0; ts < 10; ++ts) v += lds[ts * 225 + tid];
        red[tid] = v;
    }
    __syncthreads();
    if (tid < 25) {
        const float* r = &red[tid * 9];
        float mu0=r[0]*inv_n, mu1=r[1]*inv_n, mu2=r[2]*inv_n;
        float m00=r[3]*inv_n, m01=r[4]*inv_n, m02=r[5]*inv_n;
        float m11=r[6]*inv_n, m12=r[7]*inv_n, m22=r[8]*inv_n;
        float* o = &outm[tid * 16];
        o[0]=m00; o[1]=m01; o[2]=m02; o[3]=mu0;
        o[4]=m01; o[5]=m11; o[6]=m12; o[7]=mu1;
        o[8]=m02; o[9]=m12; o[10]=m22; o[11]=mu2;
        o[12]=mu0; o[13]=mu1; o[14]=mu2; o[15]=1.0f;
    }
    __syncthreads();
    int so0 = (stype == 0) ? 0 : (stype == 1) ? 1 : 3;
    int ndup = (stype == 0) ? 1 : (stype == 1) ? 2 : 3;
    int total = 400 * ndup;
    size_t obase = (size_t)b * 36000 + (size_t)chunk * 80;
    for (int idx = tid; idx < total; idx += 256) {
        int dup = idx / 400;
        int r = idx % 400;
        int np = r / 80;
        int rem = r % 80;
        out[obase + (size_t)(so0 + dup) * 6000 + (size_t)np * 1200 + rem] = outm[r];
    }
}

// ---------------- Host ----------------
static void build_tab(Tab& tab) {
    unsigned char isb[2049];
    for (int i = 0; i <= 2048; ++i) isb[i] = 0;
    isb[2048] = 1;
    for (int k = 1; k <= 14; ++k) { isb[45 * k] = 1; isb[68 * k] = 1; isb[136 * k] = 1; }
    int n = 0, prev = 0;
    int pf0[NSEG_MAX];
    for (int f = 1; f <= 2048; ++f) {
        if (!isb[f]) continue;
        pf0[n] = prev;
        tab.p[n++] = (uint32_t)(prev | ((f - prev) << 16));
        prev = f;
    }
    tab.n = n;   // 36
    const int nst[3] = {136, 68, 45};
    for (int st = 0; st < 3; ++st) {
        int ns = nst[st];
        for (int c = 0; c < 15; ++c) {
            int a = c * ns, bnd = (c == 14) ? 2048 : (c + 1) * ns;
            int p0 = 0; while (p0 < n && pf0[p0] < a) ++p0;
            int p1 = p0; while (p1 < n && pf0[p1] < bnd) ++p1;
            tab.cr[st * 15 + c] = (uint32_t)(p0 | (p1 << 16));
        }
    }
}

extern "C" void kernel_launch(void* const* d_in, const int* in_sizes, int n_in,
                              void* d_out, int out_size, void* d_ws, size_t ws_size,
                              hipStream_t stream) {
    const float* x = (const float*)d_in[0];
    float* out = (float*)d_out;
    Tab tab;
    build_tab(tab);
    size_t need = (size_t)256 * tab.n * 225 * sizeof(float);   // ~8.3 MB

    if (ws_size >= need) {
        float* ws = (float*)d_ws;
        dim3 g1(tab.n, 256);
        p1_kernel<<<g1, 256, 0, stream>>>(x, ws, tab);
        dim3 g2(256, 5);
        p2_kernel<<<g2, 256, 0, stream>>>(ws, out, tab);
    } else {
        gauss_fallback<<<256 * 45, 256, 0, stream>>>(x, out);
    }
}